// Round 1
// baseline (164.683 us; speedup 1.0000x reference)
//
#include <hip/hip_runtime.h>
#include <math.h>

#define BATCH 2
#define NTOK  256
#define NATOM 2048
#define TL 128
#define TM 128

__device__ __forceinline__ float sigf(float z) {
    return 1.0f / (1.0f + __expf(-z));
}

// ---------------- prep: token cumsum -> per-atom folded features ----------------
__global__ void prep_kernel(const float* __restrict__ is_p,
                            const float* __restrict__ is_d,
                            const float* __restrict__ is_r,
                            const float* __restrict__ is_l,
                            const float* __restrict__ tok_mask,
                            const int*   __restrict__ npt,
                            int*   __restrict__ a_tok,
                            float* __restrict__ a_isl,
                            float* __restrict__ a_poly,
                            float* __restrict__ a_nuc,
                            float* __restrict__ a_w,
                            float* __restrict__ acc) {
    int b = blockIdx.x, tid = threadIdx.x;
    __shared__ int s_cum[NTOK];
    __shared__ float s_isl[NTOK], s_poly[NTOK], s_nuc[NTOK], s_w[NTOK], s_tm[NTOK];
    int n = npt[b * NTOK + tid];
    s_cum[tid] = n;
    float pd = is_d[b * NTOK + tid], pr = is_r[b * NTOK + tid];
    float pp = is_p[b * NTOK + tid], pl = is_l[b * NTOK + tid];
    s_isl[tid]  = pl;
    s_poly[tid] = pp + pd + pr;
    s_nuc[tid]  = pd + pr;
    s_w[tid]    = 1.0f + 5.0f * pd + 5.0f * pr + 10.0f * pl;
    s_tm[tid]   = tok_mask[b * NTOK + tid];
    __syncthreads();
    // Hillis-Steele inclusive scan
    for (int off = 1; off < NTOK; off <<= 1) {
        int v = (tid >= off) ? s_cum[tid - off] : 0;
        __syncthreads();
        s_cum[tid] += v;
        __syncthreads();
    }
    int total = s_cum[NTOK - 1];
    for (int l = tid; l < NATOM; l += NTOK) {
        int tok = 0; float oh = 0.0f;
        if (l < total) {
            int lo = 0, hi = NTOK - 1;
            while (lo < hi) { int mid = (lo + hi) >> 1; if (s_cum[mid] > l) hi = mid; else lo = mid + 1; }
            tok = lo;
            oh = s_tm[tok];
        }
        a_tok[b * NATOM + l]  = tok;
        a_isl[b * NATOM + l]  = s_isl[tok]  * oh;
        a_poly[b * NATOM + l] = s_poly[tok] * oh;
        a_nuc[b * NATOM + l]  = s_nuc[tok]  * oh;
        a_w[b * NATOM + l]    = s_w[tok]    * oh;
    }
    if (tid < 8) acc[b * 8 + tid] = 0.0f;   // zero accumulators (ws is poisoned 0xAA)
}

// ---------------- weighted rigid align (Kabsch) + weighted MSE ----------------
// Reference call: _weighted_rigid_align(x=GT, x_gt=X, w=w_atom, mask=gt_mask)
// gt_al[a] = R (GT[a] - muG) + muX;  l_mse = (1/3) sum w*m*||X - gt_al||^2 / sum m
__global__ void align_kernel(const float* __restrict__ x,
                             const float* __restrict__ gt,
                             const float* __restrict__ gmask,
                             const float* __restrict__ a_w,
                             float* __restrict__ acc) {
    int b = blockIdx.x, tid = threadIdx.x;
    const float* X = x + (size_t)b * NATOM * 3;
    const float* G = gt + (size_t)b * NATOM * 3;
    const float* M = gmask + (size_t)b * NATOM;
    const float* W = a_w + (size_t)b * NATOM;
    __shared__ double red[256];
    __shared__ double sh[9];
    __shared__ double s_R[9], s_mu[6];

    // phase 1: masksum, wmsum, sum(X*wm), sum(G*wm)
    double p[8] = {0, 0, 0, 0, 0, 0, 0, 0};
    for (int a = tid; a < NATOM; a += 256) {
        double m = M[a], w = W[a];
        double wm = w * m;
        p[0] += m; p[1] += wm;
        p[2] += (double)X[a * 3 + 0] * wm; p[3] += (double)X[a * 3 + 1] * wm; p[4] += (double)X[a * 3 + 2] * wm;
        p[5] += (double)G[a * 3 + 0] * wm; p[6] += (double)G[a * 3 + 1] * wm; p[7] += (double)G[a * 3 + 2] * wm;
    }
    for (int q = 0; q < 8; ++q) {
        red[tid] = p[q]; __syncthreads();
        for (int s = 128; s > 0; s >>= 1) { if (tid < s) red[tid] += red[tid + s]; __syncthreads(); }
        if (tid == 0) sh[q] = red[0];
        __syncthreads();
    }
    double masksum = sh[0], wmsum = sh[1];
    double mux0 = sh[2] / wmsum, mux1 = sh[3] / wmsum, mux2 = sh[4] / wmsum;
    double mug0 = sh[5] / wmsum, mug1 = sh[6] / wmsum, mug2 = sh[7] / wmsum;

    // phase 2: H_ij = sum wm * (X_i - muX_i) * (G_j - muG_j)
    double h[9] = {0, 0, 0, 0, 0, 0, 0, 0, 0};
    for (int a = tid; a < NATOM; a += 256) {
        double m = M[a], w = W[a];
        double wm = w * m;
        double xc0 = (double)X[a * 3 + 0] - mux0, xc1 = (double)X[a * 3 + 1] - mux1, xc2 = (double)X[a * 3 + 2] - mux2;
        double gc0 = (double)G[a * 3 + 0] - mug0, gc1 = (double)G[a * 3 + 1] - mug1, gc2 = (double)G[a * 3 + 2] - mug2;
        h[0] += wm * xc0 * gc0; h[1] += wm * xc0 * gc1; h[2] += wm * xc0 * gc2;
        h[3] += wm * xc1 * gc0; h[4] += wm * xc1 * gc1; h[5] += wm * xc1 * gc2;
        h[6] += wm * xc2 * gc0; h[7] += wm * xc2 * gc1; h[8] += wm * xc2 * gc2;
    }
    for (int q = 0; q < 9; ++q) {
        red[tid] = h[q]; __syncthreads();
        for (int s = 128; s > 0; s >>= 1) { if (tid < s) red[tid] += red[tid + s]; __syncthreads(); }
        if (tid == 0) sh[q] = red[0];
        __syncthreads();
    }

    // phase 3 (thread 0): 3x3 SVD via Jacobi on H^T H, build R = U diag(1,1,sgn) V^T
    if (tid == 0) {
        double H[3][3];
        for (int i = 0; i < 3; i++) for (int j = 0; j < 3; j++) H[i][j] = sh[i * 3 + j];
        double A[3][3];
        for (int j = 0; j < 3; j++) for (int k = 0; k < 3; k++) {
            double s = 0; for (int i = 0; i < 3; i++) s += H[i][j] * H[i][k];
            A[j][k] = s;
        }
        double V[3][3] = {{1, 0, 0}, {0, 1, 0}, {0, 0, 1}};
        for (int sweep = 0; sweep < 30; ++sweep) {
            double off = fabs(A[0][1]) + fabs(A[0][2]) + fabs(A[1][2]);
            double diag = fabs(A[0][0]) + fabs(A[1][1]) + fabs(A[2][2]);
            if (off < 1e-14 * (diag + 1e-300)) break;
            for (int pi = 0; pi < 3; ++pi) {
                int pp_ = (pi == 2) ? 1 : 0;
                int qq_ = (pi == 0) ? 1 : 2;
                double apq = A[pp_][qq_];
                if (fabs(apq) < 1e-300) continue;
                double theta = (A[qq_][qq_] - A[pp_][pp_]) / (2.0 * apq);
                double t_ = ((theta >= 0) ? 1.0 : -1.0) / (fabs(theta) + sqrt(theta * theta + 1.0));
                double c_ = 1.0 / sqrt(t_ * t_ + 1.0), sn = t_ * c_;
                for (int k = 0; k < 3; k++) { double akp = A[k][pp_], akq = A[k][qq_];
                    A[k][pp_] = c_ * akp - sn * akq; A[k][qq_] = sn * akp + c_ * akq; }
                for (int k = 0; k < 3; k++) { double apk = A[pp_][k], aqk = A[qq_][k];
                    A[pp_][k] = c_ * apk - sn * aqk; A[qq_][k] = sn * apk + c_ * aqk; }
                for (int k = 0; k < 3; k++) { double vkp = V[k][pp_], vkq = V[k][qq_];
                    V[k][pp_] = c_ * vkp - sn * vkq; V[k][qq_] = sn * vkp + c_ * vkq; }
            }
        }
        double lam[3] = {A[0][0], A[1][1], A[2][2]};
        int idx[3] = {0, 1, 2};
        for (int i = 0; i < 2; i++) for (int j = i + 1; j < 3; j++)
            if (lam[idx[j]] > lam[idx[i]]) { int tsw = idx[i]; idx[i] = idx[j]; idx[j] = tsw; }
        double Vs[3][3], sv[3];
        for (int k = 0; k < 3; k++) {
            sv[k] = sqrt(fmax(lam[idx[k]], 0.0));
            for (int i = 0; i < 3; i++) Vs[i][k] = V[i][idx[k]];
        }
        double U[3][3] = {{1, 0, 0}, {0, 1, 0}, {0, 0, 1}};
        for (int k = 0; k < 3; k++) {
            if (sv[k] > 1e-12 * sv[0] + 1e-300) {
                for (int i = 0; i < 3; i++) {
                    double s = 0; for (int j = 0; j < 3; j++) s += H[i][j] * Vs[j][k];
                    U[i][k] = s / sv[k];
                }
            } else if (k == 2) {
                U[0][2] = U[1][0] * U[2][1] - U[2][0] * U[1][1];
                U[1][2] = U[2][0] * U[0][1] - U[0][0] * U[2][1];
                U[2][2] = U[0][0] * U[1][1] - U[1][0] * U[0][1];
            }
        }
        double R0[3][3];
        for (int i = 0; i < 3; i++) for (int j = 0; j < 3; j++) {
            double s = 0; for (int k = 0; k < 3; k++) s += U[i][k] * Vs[j][k];
            R0[i][j] = s;
        }
        double det = R0[0][0] * (R0[1][1] * R0[2][2] - R0[1][2] * R0[2][1])
                   - R0[0][1] * (R0[1][0] * R0[2][2] - R0[1][2] * R0[2][0])
                   + R0[0][2] * (R0[1][0] * R0[2][1] - R0[1][1] * R0[2][0]);
        double dk[3] = {1.0, 1.0, (det < 0.0) ? -1.0 : 1.0};
        for (int i = 0; i < 3; i++) for (int j = 0; j < 3; j++) {
            double s = 0; for (int k = 0; k < 3; k++) s += U[i][k] * dk[k] * Vs[j][k];
            s_R[i * 3 + j] = s;
        }
        s_mu[0] = mux0; s_mu[1] = mux1; s_mu[2] = mux2;
        s_mu[3] = mug0; s_mu[4] = mug1; s_mu[5] = mug2;
    }
    __syncthreads();

    // phase 4: weighted MSE
    float R00 = (float)s_R[0], R01 = (float)s_R[1], R02 = (float)s_R[2];
    float R10 = (float)s_R[3], R11 = (float)s_R[4], R12 = (float)s_R[5];
    float R20 = (float)s_R[6], R21 = (float)s_R[7], R22 = (float)s_R[8];
    float fmux0 = (float)s_mu[0], fmux1 = (float)s_mu[1], fmux2 = (float)s_mu[2];
    float fmug0 = (float)s_mu[3], fmug1 = (float)s_mu[4], fmug2 = (float)s_mu[5];
    double part = 0.0;
    for (int a = tid; a < NATOM; a += 256) {
        float m = M[a], w = W[a];
        float gc0 = G[a * 3 + 0] - fmug0, gc1 = G[a * 3 + 1] - fmug1, gc2 = G[a * 3 + 2] - fmug2;
        float al0 = R00 * gc0 + R01 * gc1 + R02 * gc2 + fmux0;
        float al1 = R10 * gc0 + R11 * gc1 + R12 * gc2 + fmux1;
        float al2 = R20 * gc0 + R21 * gc1 + R22 * gc2 + fmux2;
        float r0 = X[a * 3 + 0] - al0, r1 = X[a * 3 + 1] - al1, r2 = X[a * 3 + 2] - al2;
        part += (double)(w * m * (r0 * r0 + r1 * r1 + r2 * r2));
    }
    red[tid] = part; __syncthreads();
    for (int s = 128; s > 0; s >>= 1) { if (tid < s) red[tid] += red[tid + s]; __syncthreads(); }
    if (tid == 0) acc[b * 8 + 5] = (float)(red[0] / (3.0 * masksum));
}

// ---------------- pairwise: bond loss + smooth LDDT accumulators ----------------
__global__ __launch_bounds__(256) void pair_kernel(
    const float* __restrict__ x, const float* __restrict__ gt,
    const float* __restrict__ gmask, const float* __restrict__ tb,
    const int* __restrict__ a_tok, const float* __restrict__ a_isl,
    const float* __restrict__ a_poly, const float* __restrict__ a_nuc,
    float* __restrict__ acc)
{
    int b = blockIdx.z;
    int l0 = blockIdx.x * TL, m0 = blockIdx.y * TM;
    int tid = threadIdx.x;
    __shared__ float s_xl[TL * 3], s_gl[TL * 3], s_xm[TM * 3], s_gm[TM * 3];
    __shared__ float s_nucl[TL], s_isll[TL], s_ml[TL];
    __shared__ float s_polym[TM], s_mm[TM];
    __shared__ int s_tokl[TL], s_tokm[TM];

    const float* Xb = x + (size_t)b * NATOM * 3;
    const float* Gb = gt + (size_t)b * NATOM * 3;
    for (int i = tid; i < TL * 3; i += 256) {
        s_xl[i] = Xb[l0 * 3 + i];
        s_gl[i] = Gb[l0 * 3 + i];
        s_xm[i] = Xb[m0 * 3 + i];
        s_gm[i] = Gb[m0 * 3 + i];
    }
    for (int i = tid; i < TL; i += 256) {
        s_nucl[i]  = a_nuc[b * NATOM + l0 + i];
        s_isll[i]  = a_isl[b * NATOM + l0 + i];
        s_ml[i]    = gmask[b * NATOM + l0 + i];
        s_tokl[i]  = a_tok[b * NATOM + l0 + i];
        s_polym[i] = a_poly[b * NATOM + m0 + i];
        s_mm[i]    = gmask[b * NATOM + m0 + i];
        s_tokm[i]  = a_tok[b * NATOM + m0 + i];
    }
    __syncthreads();

    int lt = tid & (TL - 1);
    int half = tid >> 7;   // 0/1: which 64-column slice
    float xlx = s_xl[lt * 3], xly = s_xl[lt * 3 + 1], xlz = s_xl[lt * 3 + 2];
    float glx = s_gl[lt * 3], gly = s_gl[lt * 3 + 1], glz = s_gl[lt * 3 + 2];
    float nucl = s_nucl[lt], isll = s_isll[lt], ml = s_ml[lt];
    const float* tbrow = tb + ((size_t)b * NTOK + s_tokl[lt]) * NTOK;
    int gl = l0 + lt;
    float bnum = 0, bden = 0, ce = 0, cs = 0, ms = 0;
    int mstart = half * (TM / 2), mend = mstart + TM / 2;
    for (int mm = mstart; mm < mend; ++mm) {
        float dx0 = xlx - s_xm[mm * 3], dx1 = xly - s_xm[mm * 3 + 1], dx2 = xlz - s_xm[mm * 3 + 2];
        float dxv = sqrtf(dx0 * dx0 + dx1 * dx1 + dx2 * dx2 + 1e-12f);
        float dg0 = glx - s_gm[mm * 3], dg1 = gly - s_gm[mm * 3 + 1], dg2 = glz - s_gm[mm * 3 + 2];
        float dgv = sqrtf(dg0 * dg0 + dg1 * dg1 + dg2 * dg2 + 1e-12f);
        float pm = ml * s_mm[mm];
        float diff = dxv - dgv;
        float bmv = tbrow[s_tokm[mm]] * isll * s_polym[mm] * pm;
        bnum += diff * diff * bmv;
        bden += bmv;
        float d = fabsf(diff);
        float e = 0.25f * (sigf(0.5f - d) + sigf(1.0f - d) + sigf(2.0f - d) + sigf(4.0f - d));
        float c = (dgv < 30.0f ? nucl : 0.0f) + (dgv < 15.0f ? (1.0f - nucl) : 0.0f);
        float m2 = (gl != (m0 + mm)) ? pm : 0.0f;
        float cm2 = c * m2;
        ce += cm2 * e; cs += cm2; ms += m2;
    }

    __shared__ float red[256];
    float vals[5] = {bnum, bden, ce, cs, ms};
    for (int q = 0; q < 5; ++q) {
        red[tid] = vals[q]; __syncthreads();
        for (int s = 128; s > 0; s >>= 1) { if (tid < s) red[tid] += red[tid + s]; __syncthreads(); }
        if (tid == 0) atomicAdd(&acc[b * 8 + q], red[0]);
        __syncthreads();
    }
}

// ---------------- combine ----------------
__global__ void final_kernel(const float* __restrict__ acc, const float* __restrict__ t,
                             float* __restrict__ out) {
    if (threadIdx.x == 0 && blockIdx.x == 0) {
        float total = 0.0f;
        for (int b = 0; b < BATCH; ++b) {
            float bnum = acc[b * 8 + 0], bden = acc[b * 8 + 1];
            float ce = acc[b * 8 + 2], cs = acc[b * 8 + 3];
            float l_mse = acc[b * 8 + 5];
            float l_bond = bnum / bden;
            float l_lddt = 1.0f - ce / cs;   // msum cancels: (ce/ms)/(cs/ms)
            float tt = t[b];
            float w_t = (tt * tt + 256.0f) / ((tt + 16.0f) * (tt + 16.0f));
            total += w_t * (l_mse + l_bond) + l_lddt;
        }
        out[0] = total / (float)BATCH;
    }
}

extern "C" void kernel_launch(void* const* d_in, const int* in_sizes, int n_in,
                              void* d_out, int out_size, void* d_ws, size_t ws_size,
                              hipStream_t stream) {
    const float* x     = (const float*)d_in[0];
    const float* gt    = (const float*)d_in[1];
    const float* gmask = (const float*)d_in[2];
    const float* is_p  = (const float*)d_in[3];
    const float* is_d  = (const float*)d_in[4];
    const float* is_r  = (const float*)d_in[5];
    const float* is_l  = (const float*)d_in[6];
    const float* tb    = (const float*)d_in[7];
    const float* tm    = (const float*)d_in[8];
    const int*   npt   = (const int*)d_in[9];
    const float* t     = (const float*)d_in[10];
    float* out = (float*)d_out;

    char* ws = (char*)d_ws;
    int*   a_tok  = (int*)ws;                                   // B*A ints
    float* a_isl  = (float*)(ws + (size_t)BATCH * NATOM * 4);
    float* a_poly = a_isl  + BATCH * NATOM;
    float* a_nuc  = a_poly + BATCH * NATOM;
    float* a_w    = a_nuc  + BATCH * NATOM;
    float* acc    = a_w    + BATCH * NATOM;                     // B*8 floats

    prep_kernel<<<BATCH, NTOK, 0, stream>>>(is_p, is_d, is_r, is_l, tm, npt,
                                            a_tok, a_isl, a_poly, a_nuc, a_w, acc);
    align_kernel<<<BATCH, 256, 0, stream>>>(x, gt, gmask, a_w, acc);
    dim3 pg(NATOM / TL, NATOM / TM, BATCH);
    pair_kernel<<<pg, 256, 0, stream>>>(x, gt, gmask, tb, a_tok, a_isl, a_poly, a_nuc, acc);
    final_kernel<<<1, 64, 0, stream>>>(acc, t, out);
}

// Round 2
// 115.037 us; speedup vs baseline: 1.4316x; 1.4316x over previous
//
#include <hip/hip_runtime.h>
#include <math.h>

#define BATCH 2
#define NTOK  256
#define NATOM 2048
#define TL 128
#define TM 128
#define TBBUF 1600

__device__ __forceinline__ float frcp(float x)  { return __builtin_amdgcn_rcpf(x); }
__device__ __forceinline__ float fsqrt_(float x){ return __builtin_amdgcn_sqrtf(x); }

__device__ __forceinline__ double wred64(double v) {
    for (int o = 32; o > 0; o >>= 1) v += __shfl_down(v, o, 64);
    return v;
}
__device__ __forceinline__ float fred64(float v) {
    for (int o = 32; o > 0; o >>= 1) v += __shfl_down(v, o, 64);
    return v;
}

// ============ fused prep (token->atom) + weighted rigid align + MSE ============
__global__ __launch_bounds__(256) void prep_align_kernel(
    const float* __restrict__ x, const float* __restrict__ gt,
    const float* __restrict__ gmask,
    const float* __restrict__ is_p, const float* __restrict__ is_d,
    const float* __restrict__ is_r, const float* __restrict__ is_l,
    const float* __restrict__ tok_mask, const int* __restrict__ npt,
    int* __restrict__ a_tok, float* __restrict__ a_isl,
    float* __restrict__ a_poly, float* __restrict__ a_nuc,
    float* __restrict__ a_w, float* __restrict__ acc)
{
    int b = blockIdx.x, tid = threadIdx.x;
    __shared__ int s_cum[NTOK];
    __shared__ float s_isl[NTOK], s_poly[NTOK], s_nuc[NTOK], s_w[NTOK], s_tm[NTOK];

    // ---- prep phase ----
    {
        s_cum[tid] = npt[b * NTOK + tid];
        float pd = is_d[b * NTOK + tid], pr = is_r[b * NTOK + tid];
        float pp = is_p[b * NTOK + tid], pl = is_l[b * NTOK + tid];
        s_isl[tid]  = pl;
        s_poly[tid] = pp + pd + pr;
        s_nuc[tid]  = pd + pr;
        s_w[tid]    = 1.0f + 5.0f * pd + 5.0f * pr + 10.0f * pl;
        s_tm[tid]   = tok_mask[b * NTOK + tid];
        __syncthreads();
        for (int off = 1; off < NTOK; off <<= 1) {
            int v = (tid >= off) ? s_cum[tid - off] : 0;
            __syncthreads();
            s_cum[tid] += v;
            __syncthreads();
        }
        int total = s_cum[NTOK - 1];
        for (int l = tid; l < NATOM; l += NTOK) {
            int tok = 0; float oh = 0.0f;
            if (l < total) {
                int lo = 0, hi = NTOK - 1;
                while (lo < hi) { int mid = (lo + hi) >> 1; if (s_cum[mid] > l) hi = mid; else lo = mid + 1; }
                tok = lo;
                oh = s_tm[tok];
            }
            a_tok[b * NATOM + l]  = tok;
            a_isl[b * NATOM + l]  = s_isl[tok]  * oh;
            a_poly[b * NATOM + l] = s_poly[tok] * oh;
            a_nuc[b * NATOM + l]  = s_nuc[tok]  * oh;
            a_w[b * NATOM + l]    = s_w[tok]    * oh;
        }
        if (tid < 8) acc[b * 8 + tid] = 0.0f;
    }
    __syncthreads();

    // ---- align phase: single pass, 17 double accumulators ----
    const float* X = x + (size_t)b * NATOM * 3;
    const float* G = gt + (size_t)b * NATOM * 3;
    const float* M = gmask + (size_t)b * NATOM;
    const float* W = a_w + (size_t)b * NATOM;

    double p[17];
    #pragma unroll
    for (int q = 0; q < 17; q++) p[q] = 0.0;
    for (int a = tid; a < NATOM; a += 256) {
        double m = M[a], w = W[a], wm = w * m;
        double x0 = X[a * 3], x1 = X[a * 3 + 1], x2 = X[a * 3 + 2];
        double g0 = G[a * 3], g1 = G[a * 3 + 1], g2 = G[a * 3 + 2];
        p[0] += m; p[1] += wm;
        p[2] += wm * x0; p[3] += wm * x1; p[4] += wm * x2;
        p[5] += wm * g0; p[6] += wm * g1; p[7] += wm * g2;
        p[8]  += wm * x0 * g0; p[9]  += wm * x0 * g1; p[10] += wm * x0 * g2;
        p[11] += wm * x1 * g0; p[12] += wm * x1 * g1; p[13] += wm * x1 * g2;
        p[14] += wm * x2 * g0; p[15] += wm * x2 * g1; p[16] += wm * x2 * g2;
    }
    __shared__ double s_wred[4 * 17];
    int lane = tid & 63, wv = tid >> 6;
    #pragma unroll
    for (int q = 0; q < 17; q++) {
        double v = wred64(p[q]);
        if (lane == 0) s_wred[wv * 17 + q] = v;
    }
    __syncthreads();

    __shared__ float s_Rf[9], s_muf[6];
    __shared__ double s_msum;
    if (tid == 0) {
        double sh[17];
        for (int q = 0; q < 17; q++)
            sh[q] = s_wred[q] + s_wred[17 + q] + s_wred[34 + q] + s_wred[51 + q];
        double masksum = sh[0], wmsum = sh[1];
        // centered H_ij = sum wm*Xc_i*Gc_j = S_ij - sx_i*sg_j/wmsum
        double H[3][3];
        for (int i = 0; i < 3; i++)
            for (int j = 0; j < 3; j++)
                H[i][j] = sh[8 + i * 3 + j] - sh[2 + i] * sh[5 + j] / wmsum;
        // Jacobi on H^T H
        double A[3][3];
        for (int j = 0; j < 3; j++) for (int k = 0; k < 3; k++) {
            double s = 0; for (int i = 0; i < 3; i++) s += H[i][j] * H[i][k];
            A[j][k] = s;
        }
        double V[3][3] = {{1, 0, 0}, {0, 1, 0}, {0, 0, 1}};
        for (int sweep = 0; sweep < 10; ++sweep) {
            double off = fabs(A[0][1]) + fabs(A[0][2]) + fabs(A[1][2]);
            double diag = fabs(A[0][0]) + fabs(A[1][1]) + fabs(A[2][2]);
            if (off < 1e-13 * (diag + 1e-300)) break;
            for (int pi = 0; pi < 3; ++pi) {
                int pp_ = (pi == 2) ? 1 : 0;
                int qq_ = (pi == 0) ? 1 : 2;
                double apq = A[pp_][qq_];
                if (fabs(apq) < 1e-300) continue;
                double theta = (A[qq_][qq_] - A[pp_][pp_]) / (2.0 * apq);
                double t_ = ((theta >= 0) ? 1.0 : -1.0) / (fabs(theta) + sqrt(theta * theta + 1.0));
                double c_ = 1.0 / sqrt(t_ * t_ + 1.0), sn = t_ * c_;
                for (int k = 0; k < 3; k++) { double akp = A[k][pp_], akq = A[k][qq_];
                    A[k][pp_] = c_ * akp - sn * akq; A[k][qq_] = sn * akp + c_ * akq; }
                for (int k = 0; k < 3; k++) { double apk = A[pp_][k], aqk = A[qq_][k];
                    A[pp_][k] = c_ * apk - sn * aqk; A[qq_][k] = sn * apk + c_ * aqk; }
                for (int k = 0; k < 3; k++) { double vkp = V[k][pp_], vkq = V[k][qq_];
                    V[k][pp_] = c_ * vkp - sn * vkq; V[k][qq_] = sn * vkp + c_ * vkq; }
            }
        }
        double lam[3] = {A[0][0], A[1][1], A[2][2]};
        int idx[3] = {0, 1, 2};
        for (int i = 0; i < 2; i++) for (int j = i + 1; j < 3; j++)
            if (lam[idx[j]] > lam[idx[i]]) { int tsw = idx[i]; idx[i] = idx[j]; idx[j] = tsw; }
        double Vs[3][3], sv[3];
        for (int k = 0; k < 3; k++) {
            sv[k] = sqrt(fmax(lam[idx[k]], 0.0));
            for (int i = 0; i < 3; i++) Vs[i][k] = V[i][idx[k]];
        }
        double U[3][3] = {{1, 0, 0}, {0, 1, 0}, {0, 0, 1}};
        for (int k = 0; k < 3; k++) {
            if (sv[k] > 1e-12 * sv[0] + 1e-300) {
                for (int i = 0; i < 3; i++) {
                    double s = 0; for (int j = 0; j < 3; j++) s += H[i][j] * Vs[j][k];
                    U[i][k] = s / sv[k];
                }
            } else if (k == 2) {
                U[0][2] = U[1][0] * U[2][1] - U[2][0] * U[1][1];
                U[1][2] = U[2][0] * U[0][1] - U[0][0] * U[2][1];
                U[2][2] = U[0][0] * U[1][1] - U[1][0] * U[0][1];
            }
        }
        double R0[3][3];
        for (int i = 0; i < 3; i++) for (int j = 0; j < 3; j++) {
            double s = 0; for (int k = 0; k < 3; k++) s += U[i][k] * Vs[j][k];
            R0[i][j] = s;
        }
        double det = R0[0][0] * (R0[1][1] * R0[2][2] - R0[1][2] * R0[2][1])
                   - R0[0][1] * (R0[1][0] * R0[2][2] - R0[1][2] * R0[2][0])
                   + R0[0][2] * (R0[1][0] * R0[2][1] - R0[1][1] * R0[2][0]);
        double dk[3] = {1.0, 1.0, (det < 0.0) ? -1.0 : 1.0};
        for (int i = 0; i < 3; i++) for (int j = 0; j < 3; j++) {
            double s = 0; for (int k = 0; k < 3; k++) s += U[i][k] * dk[k] * Vs[j][k];
            s_Rf[i * 3 + j] = (float)s;
        }
        for (int i = 0; i < 3; i++) { s_muf[i] = (float)(sh[2 + i] / wmsum); s_muf[3 + i] = (float)(sh[5 + i] / wmsum); }
        s_msum = masksum;
    }
    __syncthreads();

    // ---- MSE pass ----
    float R00 = s_Rf[0], R01 = s_Rf[1], R02 = s_Rf[2];
    float R10 = s_Rf[3], R11 = s_Rf[4], R12 = s_Rf[5];
    float R20 = s_Rf[6], R21 = s_Rf[7], R22 = s_Rf[8];
    float mux0 = s_muf[0], mux1 = s_muf[1], mux2 = s_muf[2];
    float mug0 = s_muf[3], mug1 = s_muf[4], mug2 = s_muf[5];
    double part = 0.0;
    for (int a = tid; a < NATOM; a += 256) {
        float m = M[a], w = W[a];
        float gc0 = G[a * 3] - mug0, gc1 = G[a * 3 + 1] - mug1, gc2 = G[a * 3 + 2] - mug2;
        float al0 = R00 * gc0 + R01 * gc1 + R02 * gc2 + mux0;
        float al1 = R10 * gc0 + R11 * gc1 + R12 * gc2 + mux1;
        float al2 = R20 * gc0 + R21 * gc1 + R22 * gc2 + mux2;
        float r0 = X[a * 3] - al0, r1 = X[a * 3 + 1] - al1, r2 = X[a * 3 + 2] - al2;
        part += (double)(w * m * (r0 * r0 + r1 * r1 + r2 * r2));
    }
    double v = wred64(part);
    if (lane == 0) s_wred[wv] = v;
    __syncthreads();
    if (tid == 0)
        acc[b * 8 + 5] = (float)((s_wred[0] + s_wred[1] + s_wred[2] + s_wred[3]) / (3.0 * s_msum));
}

// ============ pairwise: bond loss + smooth LDDT ============
__global__ __launch_bounds__(256) void pair_kernel(
    const float* __restrict__ x, const float* __restrict__ gt,
    const float* __restrict__ gmask, const float* __restrict__ tb,
    const int* __restrict__ a_tok, const float* __restrict__ a_isl,
    const float* __restrict__ a_poly, const float* __restrict__ a_nuc,
    float* __restrict__ acc)
{
    int b = blockIdx.z;
    int l0 = blockIdx.x * TL, m0 = blockIdx.y * TM;
    int tid = threadIdx.x;
    __shared__ float4 s_lx[TL], s_lg[TL], s_mx[TM], s_mg[TM];
    __shared__ float s_lnuc[TL];
    __shared__ int s_lrow[TL], s_mrel[TM];
    __shared__ float s_tb[TBBUF];
    __shared__ int s_info[6];

    const float* Xb = x + (size_t)b * NATOM * 3;
    const float* Gb = gt + (size_t)b * NATOM * 3;
    const float* Mb = gmask + (size_t)b * NATOM;
    const int*   Tok = a_tok + (size_t)b * NATOM;

    if (tid < TL) {
        int l = l0 + tid;
        float ml = Mb[l];
        s_lx[tid] = make_float4(Xb[l * 3], Xb[l * 3 + 1], Xb[l * 3 + 2], ml);
        s_lg[tid] = make_float4(Gb[l * 3], Gb[l * 3 + 1], Gb[l * 3 + 2], a_isl[b * NATOM + l] * ml);
        s_lnuc[tid] = a_nuc[b * NATOM + l];
    } else {
        int i = tid - TL, m = m0 + i;
        float mm = Mb[m];
        s_mx[i] = make_float4(Xb[m * 3], Xb[m * 3 + 1], Xb[m * 3 + 2], mm);
        s_mg[i] = make_float4(Gb[m * 3], Gb[m * 3 + 1], Gb[m * 3 + 2], a_poly[b * NATOM + m] * mm);
    }
    if (tid == 0) {
        int tl0 = Tok[l0], tl1 = Tok[l0 + TL - 1];
        int tm0 = Tok[m0], tm1 = Tok[m0 + TM - 1];
        int spanL = tl1 - tl0 + 1, spanM = tm1 - tm0 + 1;
        int stride = spanM | 1;
        int fits = (spanL >= 1) && (spanM >= 1) && (spanL * stride <= TBBUF);
        s_info[0] = fits; s_info[1] = stride; s_info[2] = spanM;
        s_info[3] = tl0; s_info[4] = tm0; s_info[5] = spanL;
    }
    __syncthreads();
    int fits = s_info[0], stride = s_info[1], spanM = s_info[2];
    int tl0 = s_info[3], tm0 = s_info[4], spanL = s_info[5];
    if (tid < TL) {
        int tk = Tok[l0 + tid];
        s_lrow[tid] = fits ? min(max(tk - tl0, 0), spanL - 1) * stride : tk * NTOK;
    } else {
        int tk = Tok[m0 + tid - TL];
        s_mrel[tid - TL] = fits ? min(max(tk - tm0, 0), spanM - 1) : tk;
    }
    const float* tbg = tb + (size_t)b * NTOK * NTOK;
    if (fits) {
        int cnt = spanL * stride;
        for (int i = tid; i < cnt; i += 256) {
            int r = i / stride, cc = i - r * stride;
            if (cc < spanM) s_tb[i] = tbg[(tl0 + r) * NTOK + tm0 + cc];
        }
    }
    __syncthreads();

    int lt = tid & 31, mg = tid >> 5;
    float4 lxv[4], lgv[4]; float lnu[4]; int lrw[4], gli[4];
    #pragma unroll
    for (int k = 0; k < 4; k++) {
        int li = lt + 32 * k;
        lxv[k] = s_lx[li]; lgv[k] = s_lg[li];
        lnu[k] = s_lnuc[li]; lrw[k] = s_lrow[li]; gli[k] = l0 + li;
    }
    float bnum = 0.f, bden = 0.f, ce = 0.f, cs = 0.f;
    const float k1 = 0.60653066f, k2 = 0.36787944f, k3 = 0.13533528f, k4 = 0.018315639f;

    auto body = [&](auto ldtb) {
        int mstart = mg * 16;
        #pragma unroll 2
        for (int j = 0; j < 16; j++) {
            int m = mstart + j;
            float4 mxv = s_mx[m], mgv = s_mg[m];
            int mrel = s_mrel[m];
            int gmi = m0 + m;
            #pragma unroll
            for (int k = 0; k < 4; k++) {
                float dx0 = lxv[k].x - mxv.x, dx1 = lxv[k].y - mxv.y, dx2 = lxv[k].z - mxv.z;
                float dg0 = lgv[k].x - mgv.x, dg1 = lgv[k].y - mgv.y, dg2 = lgv[k].z - mgv.z;
                float dxv = fsqrt_(fmaf(dx2, dx2, fmaf(dx1, dx1, fmaf(dx0, dx0, 1e-12f))));
                float dgv = fsqrt_(fmaf(dg2, dg2, fmaf(dg1, dg1, fmaf(dg0, dg0, 1e-12f))));
                float diff = dxv - dgv;
                float tbv = ldtb(lrw[k], mrel);
                float bmv = tbv * (lgv[k].w * mgv.w);
                bden += bmv;
                bnum = fmaf(diff * diff, bmv, bnum);
                float d = fabsf(diff);
                float u = __expf(d);              // sig(a-d) = 1/(1 + e^d * e^-a)
                float e1 = frcp(fmaf(u, k1, 1.0f));
                float e2 = frcp(fmaf(u, k2, 1.0f));
                float e3 = frcp(fmaf(u, k3, 1.0f));
                float e4 = frcp(fmaf(u, k4, 1.0f));
                float es = (e1 + e2) + (e3 + e4);
                float pm = lxv[k].w * mxv.w;
                float cc = dgv < 30.0f ? (dgv < 15.0f ? 1.0f : lnu[k]) : 0.0f;
                float pm2 = (gli[k] != gmi) ? pm : 0.0f;
                float cm2 = cc * pm2;
                cs += cm2;
                ce = fmaf(cm2 * 0.25f, es, ce);
            }
        }
    };
    if (fits) body([&](int r, int c) -> float { return s_tb[r + c]; });
    else      body([&](int r, int c) -> float { return tbg[r + c]; });

    float vals[4] = {bnum, bden, ce, cs};
    int lane = tid & 63, wv = tid >> 6;
    __shared__ float s_pred[4][4];
    #pragma unroll
    for (int q = 0; q < 4; q++) {
        float v = fred64(vals[q]);
        if (lane == 0) s_pred[wv][q] = v;
    }
    __syncthreads();
    if (tid < 4) {
        float v = s_pred[0][tid] + s_pred[1][tid] + s_pred[2][tid] + s_pred[3][tid];
        atomicAdd(&acc[b * 8 + tid], v);
    }
}

// ============ combine ============
__global__ void final_kernel(const float* __restrict__ acc, const float* __restrict__ t,
                             float* __restrict__ out) {
    if (threadIdx.x == 0 && blockIdx.x == 0) {
        float total = 0.0f;
        for (int b = 0; b < BATCH; ++b) {
            float bnum = acc[b * 8 + 0], bden = acc[b * 8 + 1];
            float ce = acc[b * 8 + 2], cs = acc[b * 8 + 3];
            float l_mse = acc[b * 8 + 5];
            float l_bond = bnum / bden;
            float l_lddt = 1.0f - ce / cs;
            float tt = t[b];
            float w_t = (tt * tt + 256.0f) / ((tt + 16.0f) * (tt + 16.0f));
            total += w_t * (l_mse + l_bond) + l_lddt;
        }
        out[0] = total / (float)BATCH;
    }
}

extern "C" void kernel_launch(void* const* d_in, const int* in_sizes, int n_in,
                              void* d_out, int out_size, void* d_ws, size_t ws_size,
                              hipStream_t stream) {
    const float* x     = (const float*)d_in[0];
    const float* gt    = (const float*)d_in[1];
    const float* gmask = (const float*)d_in[2];
    const float* is_p  = (const float*)d_in[3];
    const float* is_d  = (const float*)d_in[4];
    const float* is_r  = (const float*)d_in[5];
    const float* is_l  = (const float*)d_in[6];
    const float* tb    = (const float*)d_in[7];
    const float* tm    = (const float*)d_in[8];
    const int*   npt   = (const int*)d_in[9];
    const float* t     = (const float*)d_in[10];
    float* out = (float*)d_out;

    char* ws = (char*)d_ws;
    int*   a_tok  = (int*)ws;
    float* a_isl  = (float*)(ws + (size_t)BATCH * NATOM * 4);
    float* a_poly = a_isl  + BATCH * NATOM;
    float* a_nuc  = a_poly + BATCH * NATOM;
    float* a_w    = a_nuc  + BATCH * NATOM;
    float* acc    = a_w    + BATCH * NATOM;

    prep_align_kernel<<<BATCH, 256, 0, stream>>>(x, gt, gmask, is_p, is_d, is_r, is_l,
                                                 tm, npt, a_tok, a_isl, a_poly, a_nuc, a_w, acc);
    dim3 pg(NATOM / TL, NATOM / TM, BATCH);
    pair_kernel<<<pg, 256, 0, stream>>>(x, gt, gmask, tb, a_tok, a_isl, a_poly, a_nuc, acc);
    final_kernel<<<1, 64, 0, stream>>>(acc, t, out);
}